// Round 20
// baseline (159.328 us; speedup 1.0000x reference)
//
#include <hip/hip_runtime.h>

#define NN 20000
#define KNEI 32
#define DIM 256
#define NHEAD 8
#define HDIM 32
#define DFFN 1024
#define QKVD 768

typedef __attribute__((ext_vector_type(8))) __bf16 bf16x8;
typedef __attribute__((ext_vector_type(8))) unsigned short u16x8;
typedef __attribute__((ext_vector_type(4))) unsigned short u16x4;
typedef __attribute__((ext_vector_type(4))) float f32x4;
typedef __attribute__((ext_vector_type(2))) float f32x2;

static __device__ __forceinline__ float b2f(unsigned short u) {
    return __builtin_bit_cast(float, (unsigned)u << 16);
}
static __device__ __forceinline__ float blo(unsigned w) {
    return __builtin_bit_cast(float, w << 16);
}
static __device__ __forceinline__ float bhi(unsigned w) {
    return __builtin_bit_cast(float, w & 0xffff0000u);
}
static __device__ __forceinline__ unsigned short f2b(float f) {
    unsigned u = __builtin_bit_cast(unsigned, f);
    return (unsigned short)((u + 0x7fff + ((u >> 16) & 1)) >> 16);
}

// ---- fp8 e4m3fn encode/decode (HW builtins on device; bit-ops fallback for host pass) ----
static __device__ __forceinline__ unsigned char fp8enc(float v) {
#if defined(__HIP_DEVICE_COMPILE__) && __has_builtin(__builtin_amdgcn_cvt_pk_fp8_f32)
    return (unsigned char)(__builtin_amdgcn_cvt_pk_fp8_f32(v, v, 0u, false) & 0xffu);
#else
    unsigned u = __builtin_bit_cast(unsigned, v);
    unsigned s = u >> 31;
    unsigned a = u & 0x7fffffffu;
    if (a >= 0x43e00000u) return (unsigned char)((s << 7) | 0x7e);
    float af = __builtin_bit_cast(float, a);
    if (af < 0.015625f) {
        unsigned r = (unsigned)(af * 512.0f + 0.5f);
        if (r >= 8u) return (unsigned char)((s << 7) | 0x08);
        return (unsigned char)((s << 7) | r);
    }
    unsigned lsb = (a >> 20) & 1u;
    a += 0x7ffffu + lsb;
    unsigned e = (a >> 23) - 120u;
    unsigned m = (a >> 20) & 7u;
    unsigned code = (e << 3) | m;
    if (code > 0x7eu) code = 0x7eu;
    return (unsigned char)((s << 7) | code);
#endif
}

template<int SEL>
static __device__ __forceinline__ float fp8dec(unsigned word) {
#if defined(__HIP_DEVICE_COMPILE__) && __has_builtin(__builtin_amdgcn_cvt_f32_fp8)
    return __builtin_amdgcn_cvt_f32_fp8(word, SEL);
#else
    unsigned b = (word >> (SEL * 8)) & 0xffu;
    unsigned s = (b >> 7) & 1u;
    unsigned e = (b >> 3) & 0xfu;
    unsigned m = b & 7u;
    float v;
    if (e == 0) v = (float)m * 0.001953125f;
    else        v = __builtin_bit_cast(float, ((e + 120u) << 23) | (m << 20));
    return s ? -v : v;
#endif
}

template<bool HI>
static __device__ __forceinline__ f32x2 fp8pk(unsigned word) {
#if defined(__HIP_DEVICE_COMPILE__) && __has_builtin(__builtin_amdgcn_cvt_pk_f32_fp8)
    return __builtin_amdgcn_cvt_pk_f32_fp8((int)word, HI);
#else
    f32x2 r;
    r.x = fp8dec<HI ? 2 : 0>(word);
    r.y = fp8dec<HI ? 3 : 1>(word);
    return r;
#endif
}

#define GLD16(src, dst)                                                          \
    __builtin_amdgcn_global_load_lds(                                            \
        (const __attribute__((address_space(1))) void*)(const void*)(src),       \
        (__attribute__((address_space(3))) void*)(void*)(dst), 16, 0, 0)

// ---------------- bf16 MFMA GEMM (r12 structure) + XCD-aware block swizzle ----------------
template<int BM, int NT, int RELU, int WF32, int WBF16, int SPLIT>
__global__ __launch_bounds__(256) void gemm_mfma(const unsigned short* __restrict__ A,
                                                 const unsigned short* __restrict__ Bt,
                                                 const float* __restrict__ bias,
                                                 float* __restrict__ Cf,
                                                 unsigned short* __restrict__ Cb,
                                                 unsigned char* __restrict__ kvp,
                                                 int M, int N, int K)
{
    constexpr int BN = 128, BK = 32;
    constexpr int MI = BM / 32;
    constexpr int NI = BN / 32;

    __shared__ unsigned short As[BM * BK];
    __shared__ unsigned short Bs[BN * BK];

    const int tid  = threadIdx.x;
    const int wid  = tid >> 6;
    const int lane = tid & 63;

    // ---- bijective XCD swizzle; N-fastest within each XCD chunk ----
    const int nwg  = gridDim.x;
    const int orig = blockIdx.x;
    const int xcd  = orig & 7;
    const int pos  = orig >> 3;
    const int qc   = nwg >> 3, rc = nwg & 7;
    const int wgid = (xcd < rc ? xcd * (qc + 1) : rc * (qc + 1) + (xcd - rc) * qc) + pos;
    const int bm = (wgid / NT) * BM;
    const int bn = (wgid % NT) * BN;

    const int wr = (wid >> 1) * (BM / 2);
    const int wc = (wid & 1) * (BN / 2);
    const int r0   = lane & 15;
    const int kblk = (lane >> 4) * 8;

    f32x4 acc[MI][NI];
    #pragma unroll
    for (int i = 0; i < MI; ++i)
        #pragma unroll
        for (int j = 0; j < NI; ++j)
            acc[i][j] = (f32x4){0.f, 0.f, 0.f, 0.f};

    for (int k0 = 0; k0 < K; k0 += BK) {
        #pragma unroll
        for (int t = 0; t < (BM * 4) / 256; ++t) {
            int c = t * 256 + tid;
            int row = bm + (c >> 2);
            if (row >= M) row = M - 1;
            GLD16(A + (size_t)row * K + k0 + (c & 3) * 8,
                  &As[(t * 256 + wid * 64) * 8]);
        }
        #pragma unroll
        for (int t = 0; t < (BN * 4) / 256; ++t) {
            int c = t * 256 + tid;
            GLD16(Bt + (size_t)(bn + (c >> 2)) * K + k0 + (c & 3) * 8,
                  &Bs[(t * 256 + wid * 64) * 8]);
        }
        __syncthreads();

        bf16x8 af[MI], bfr[NI];
        #pragma unroll
        for (int mi = 0; mi < MI; ++mi)
            af[mi] = __builtin_bit_cast(bf16x8,
                     *(const u16x8*)&As[(wr + mi * 16 + r0) * BK + kblk]);
        #pragma unroll
        for (int ni = 0; ni < NI; ++ni)
            bfr[ni] = __builtin_bit_cast(bf16x8,
                     *(const u16x8*)&Bs[(wc + ni * 16 + r0) * BK + kblk]);
        #pragma unroll
        for (int mi = 0; mi < MI; ++mi)
            #pragma unroll
            for (int ni = 0; ni < NI; ++ni)
                acc[mi][ni] = __builtin_amdgcn_mfma_f32_16x16x32_bf16(
                    af[mi], bfr[ni], acc[mi][ni], 0, 0, 0);
        __syncthreads();
    }

    const int r4 = (lane >> 4) * 4;
    #pragma unroll
    for (int mi = 0; mi < MI; ++mi)
        #pragma unroll
        for (int ni = 0; ni < NI; ++ni) {
            const int col = bn + wc + ni * 16 + r0;
            const float bb = bias[col];
            #pragma unroll
            for (int r = 0; r < 4; ++r) {
                const int row = bm + wr + mi * 16 + r4 + r;
                if (row < M) {
                    float v = acc[mi][ni][r] + bb;
                    if (RELU) v = fmaxf(v, 0.f);
                    if (SPLIT) {
                        if (col < 256) {
                            Cb[(size_t)row * DIM + col] = f2b(v);
                        } else {
                            const int cc  = col - 256;          // 0..511
                            const int isV = cc >> 8;            // 0=K, 1=V
                            const int hh  = (cc & 255) >> 5;    // head 0..7
                            const int dd  = cc & 31;
                            kvp[((size_t)(hh >> 1) * NN + row) * 128
                                + isV * 64 + (hh & 1) * 32 + dd] = fp8enc(v);
                        }
                    } else {
                        if (WF32)  Cf[(size_t)row * N + col] = v;
                        if (WBF16) Cb[(size_t)row * N + col] = f2b(v);
                    }
                }
            }
        }
}

// ---------------- fused GEMM (N=256) + residual + LayerNorm epilogue (BM=32) ----------
template<int RESF32, int WFOUT>
__global__ __launch_bounds__(256) void gemm_ln(const unsigned short* __restrict__ A,
                                               const unsigned short* __restrict__ Bt,
                                               const float* __restrict__ bias,
                                               const float* __restrict__ resf,
                                               const unsigned short* __restrict__ resb,
                                               const float* __restrict__ gamma,
                                               const float* __restrict__ beta,
                                               float* __restrict__ outf,
                                               unsigned short* __restrict__ outb,
                                               int M, int K)
{
    constexpr int BM = 32, BN = 256, BK = 32;
    constexpr int NI = BN / 32;   // 8

    __shared__ unsigned short As[BM * BK];
    __shared__ unsigned short Bs[BN * BK];
    __shared__ float rs[2][BM][2];   // [col-half][local row][sum, sumsq]

    const int tid  = threadIdx.x;
    const int wid  = tid >> 6;
    const int lane = tid & 63;
    const int bm = blockIdx.x * BM;
    const int wr = (wid >> 1) * 16;          // 16-row half
    const int wc = (wid & 1) * 128;          // 128-col half
    const int r0   = lane & 15;
    const int kblk = (lane >> 4) * 8;

    f32x4 acc[NI];
    #pragma unroll
    for (int j = 0; j < NI; ++j) acc[j] = (f32x4){0.f, 0.f, 0.f, 0.f};

    for (int k0 = 0; k0 < K; k0 += BK) {
        if (wid < 2) {
            int c = tid;  // 0..127
            GLD16(A + (size_t)(bm + (c >> 2)) * K + k0 + (c & 3) * 8,
                  &As[(wid * 64) * 8]);
        }
        #pragma unroll
        for (int t = 0; t < 4; ++t) {
            int c = t * 256 + tid;
            GLD16(Bt + (size_t)(c >> 2) * K + k0 + (c & 3) * 8,
                  &Bs[(t * 256 + wid * 64) * 8]);
        }
        __syncthreads();

        bf16x8 af = __builtin_bit_cast(bf16x8,
                    *(const u16x8*)&As[(wr + r0) * BK + kblk]);
        bf16x8 bfr[NI];
        #pragma unroll
        for (int ni = 0; ni < NI; ++ni)
            bfr[ni] = __builtin_bit_cast(bf16x8,
                      *(const u16x8*)&Bs[(wc + ni * 16 + r0) * BK + kblk]);
        #pragma unroll
        for (int ni = 0; ni < NI; ++ni)
            acc[ni] = __builtin_amdgcn_mfma_f32_16x16x32_bf16(af, bfr[ni], acc[ni], 0, 0, 0);
        __syncthreads();
    }

    // ---- epilogue: v = acc + bias + residual; per-row LN over 256 cols ----
    const int r4 = (lane >> 4) * 4;
    float v[NI][4];
    float rsum[4] = {0.f, 0.f, 0.f, 0.f};
    float rsq[4]  = {0.f, 0.f, 0.f, 0.f};
    #pragma unroll
    for (int ni = 0; ni < NI; ++ni) {
        const int col = wc + ni * 16 + r0;
        const float bb = bias[col];
        #pragma unroll
        for (int r = 0; r < 4; ++r) {
            const size_t idx = (size_t)(bm + wr + r4 + r) * DIM + col;
            const float res = RESF32 ? resf[idx] : b2f(resb[idx]);
            const float val = acc[ni][r] + bb + res;
            v[ni][r] = val;
            rsum[r] += val;
            rsq[r]  += val * val;
        }
    }
    #pragma unroll
    for (int sh = 1; sh <= 8; sh <<= 1) {
        #pragma unroll
        for (int r = 0; r < 4; ++r) {
            rsum[r] += __shfl_xor(rsum[r], sh);
            rsq[r]  += __shfl_xor(rsq[r], sh);
        }
    }
    if (r0 == 0) {
        #pragma unroll
        for (int r = 0; r < 4; ++r) {
            rs[wid & 1][wr + r4 + r][0] = rsum[r];
            rs[wid & 1][wr + r4 + r][1] = rsq[r];
        }
    }
    __syncthreads();
    float mean_r[4], rstd_r[4];
    #pragma unroll
    for (int r = 0; r < 4; ++r) {
        const int lrow = wr + r4 + r;
        const float sum = rs[0][lrow][0] + rs[1][lrow][0];
        const float sq  = rs[0][lrow][1] + rs[1][lrow][1];
        const float mean = sum * (1.f / 256.f);
        mean_r[r] = mean;
        rstd_r[r] = rsqrtf(sq * (1.f / 256.f) - mean * mean + 1e-5f);
    }
    #pragma unroll
    for (int ni = 0; ni < NI; ++ni) {
        const int col = wc + ni * 16 + r0;
        const float g = gamma[col], be = beta[col];
        #pragma unroll
        for (int r = 0; r < 4; ++r) {
            const size_t idx = (size_t)(bm + wr + r4 + r) * DIM + col;
            const float ov = (v[ni][r] - mean_r[r]) * rstd_r[r] * g + be;
            if (WFOUT) outf[idx] = ov;
            else       outb[idx] = f2b(ov);
        }
    }
}

// ---------------- attention v8: TWO nodes per wave (2x ILP/MLP in latency-bound kernel) ----
// kvp[hp][node][128]: K(2hp) K(2hp+1) V(2hp) V(2hp+1), 32 B each.
// Block bid: hp = bid&3 (XCD-pinned), node base = (bid>>2)*8 + wid*2; wave handles
// nodes base, base+1 for heads (2hp, 2hp+1). All K/q loads for both nodes issue
// up-front -> 2x memory-level parallelism; node B's compute hides node A's stalls.
__global__ __launch_bounds__(256) void attn_f8(const unsigned short* __restrict__ q,
                                               const unsigned char* __restrict__ kvp,
                                               const int* __restrict__ samp,
                                               unsigned short* __restrict__ o)
{
    __shared__ int pkbuf[4][2][128];   // [wave][node-sub][hs*64 + j*2 + {p,koff}]

    const int bid = blockIdx.x;
    const int hp  = bid & 3;
    const int tid = threadIdx.x;
    const int wid = tid >> 6;
    const int lane = tid & 63;
    const int j = lane & 31;
    const int hs = lane >> 5;
    const int h = hp * 2 + hs;
    const int nbase = (bid >> 2) * 8 + wid * 2;

    // ---- issue ALL gathers up-front (both nodes) ----
    int kidx[2];
    #pragma unroll
    for (int u = 0; u < 2; ++u) kidx[u] = samp[(nbase + u) * KNEI + j];

    uint4 k0[2], k1[2];
    #pragma unroll
    for (int u = 0; u < 2; ++u) {
        const unsigned char* krow = kvp + ((size_t)hp * NN + kidx[u]) * 128 + hs * 32;
        k0[u] = *(const uint4*)krow;
        k1[u] = *(const uint4*)(krow + 16);
    }
    uint4 qv[2][4];
    #pragma unroll
    for (int u = 0; u < 2; ++u) {
        const uint4* qp = (const uint4*)(q + (size_t)(nbase + u) * DIM + h * HDIM);
        qv[u][0] = qp[0]; qv[u][1] = qp[1]; qv[u][2] = qp[2]; qv[u][3] = qp[3];
    }

    // ---- score + softmax per node ----
    #pragma unroll
    for (int u = 0; u < 2; ++u) {
        const unsigned qw[16] = {qv[u][0].x, qv[u][0].y, qv[u][0].z, qv[u][0].w,
                                 qv[u][1].x, qv[u][1].y, qv[u][1].z, qv[u][1].w,
                                 qv[u][2].x, qv[u][2].y, qv[u][2].z, qv[u][2].w,
                                 qv[u][3].x, qv[u][3].y, qv[u][3].z, qv[u][3].w};
        const unsigned kw[8] = {k0[u].x, k0[u].y, k0[u].z, k0[u].w,
                                k1[u].x, k1[u].y, k1[u].z, k1[u].w};
        float s = 0.f;
        #pragma unroll
        for (int i = 0; i < 8; ++i) {
            f32x2 ka = fp8pk<false>(kw[i]);
            f32x2 kb = fp8pk<true>(kw[i]);
            unsigned q0 = qw[2 * i], q1 = qw[2 * i + 1];
            s = fmaf(blo(q0), ka.x, s);
            s = fmaf(bhi(q0), ka.y, s);
            s = fmaf(blo(q1), kb.x, s);
            s = fmaf(bhi(q1), kb.y, s);
        }
        s *= 0.17677669529663687f;          // 1/sqrt(32)

        float m = s;
        #pragma unroll
        for (int sh = 16; sh; sh >>= 1) m = fmaxf(m, __shfl_xor(m, sh));
        float e = __expf(s - m);
        float sum = e;
        #pragma unroll
        for (int sh = 16; sh; sh >>= 1) sum += __shfl_xor(sum, sh);
        const float p = __fdividef(e, sum);

        pkbuf[wid][u][hs * 64 + j * 2]     = __builtin_bit_cast(int, p);
        pkbuf[wid][u][hs * 64 + j * 2 + 1] = kidx[u] << 7;
    }

    // ---- PV: both nodes interleaved; lane = (hs, jg, d8) ----
    const int jg = j >> 3, d8 = j & 7;
    const unsigned vconst = (unsigned)((size_t)hp * NN) * 128u + 64u + hs * 32 + d8 * 4;
    float a[2][4] = {};
    #pragma unroll
    for (int jj = 0; jj < 8; ++jj) {
        #pragma unroll
        for (int u = 0; u < 2; ++u) {
            const int jn = jg * 8 + jj;
            const int2 pk = *(const int2*)&pkbuf[wid][u][hs * 64 + jn * 2];
            const float pj = __builtin_bit_cast(float, pk.x);
            const unsigned vw = *(const unsigned*)(kvp + vconst + (unsigned)pk.y);
            f32x2 vlo = fp8pk<false>(vw);
            f32x2 vhi = fp8pk<true>(vw);
            a[u][0] = fmaf(pj, vlo.x, a[u][0]);
            a[u][1] = fmaf(pj, vlo.y, a[u][1]);
            a[u][2] = fmaf(pj, vhi.x, a[u][2]);
            a[u][3] = fmaf(pj, vhi.y, a[u][3]);
        }
    }
    #pragma unroll
    for (int u = 0; u < 2; ++u) {
        #pragma unroll
        for (int r = 0; r < 4; ++r) {
            a[u][r] += __shfl_xor(a[u][r], 8);
            a[u][r] += __shfl_xor(a[u][r], 16);
        }
        if (jg == 0) {
            u16x4 ov = { f2b(a[u][0]), f2b(a[u][1]), f2b(a[u][2]), f2b(a[u][3]) };
            *(u16x4*)(o + (size_t)(nbase + u) * DIM + h * HDIM + d8 * 4) = ov;
        }
    }
}

// ---------------- fused prep: all weight transposes + bias concat + x->bf16 ----------------
static __device__ __forceinline__ void trans_tile(const float* __restrict__ W,
                                                  unsigned short* __restrict__ T,
                                                  float (*sh)[33],
                                                  int n0, int k0, int N, int K, int tidx)
{
    const int tx = tidx & 31, ty = tidx >> 5;
    #pragma unroll
    for (int i = 0; i < 32; i += 8)
        sh[ty + i][tx] = W[(size_t)(k0 + ty + i) * N + n0 + tx];
    __syncthreads();
    #pragma unroll
    for (int i = 0; i < 32; i += 8)
        T[(size_t)(n0 + ty + i) * K + k0 + tx] = f2b(sh[tx][ty + i]);
}

__global__ __launch_bounds__(256) void prep_all(const float* __restrict__ Wq,
                                                const float* __restrict__ Wk,
                                                const float* __restrict__ Wv,
                                                const float* __restrict__ Wo,
                                                const float* __restrict__ W1,
                                                const float* __restrict__ W2,
                                                const float* __restrict__ bq,
                                                const float* __restrict__ bk,
                                                const float* __restrict__ bv,
                                                const float* __restrict__ x,
                                                unsigned short* __restrict__ WqkvT,
                                                unsigned short* __restrict__ WoT,
                                                unsigned short* __restrict__ W1T,
                                                unsigned short* __restrict__ W2T,
                                                float* __restrict__ bqkv,
                                                unsigned short* __restrict__ xb)
{
    __shared__ float sh[32][33];
    const int bid = blockIdx.x;
    const int tidx = threadIdx.x;

    if (bid < 256) {                      // 4 x [256][256] -> [256][256]^T
        const float* W; unsigned short* T;
        switch (bid >> 6) {
            case 0:  W = Wq; T = WqkvT;           break;
            case 1:  W = Wk; T = WqkvT + 65536;   break;
            case 2:  W = Wv; T = WqkvT + 131072;  break;
            default: W = Wo; T = WoT;             break;
        }
        const int t = bid & 63;
        trans_tile(W, T, sh, (t & 7) * 32, (t >> 3) * 32, DIM, DIM, tidx);
    } else if (bid < 512) {               // W1 [256][1024] -> [1024][256]
        const int t = bid - 256;
        trans_tile(W1, W1T, sh, (t & 31) * 32, (t >> 5) * 32, DFFN, DIM, tidx);
    } else if (bid < 768) {               // W2 [1024][256] -> [256][1024]
        const int t = bid - 512;
        trans_tile(W2, W2T, sh, (t & 7) * 32, (t >> 3) * 32, DIM, DFFN, tidx);
    } else if (bid == 768) {              // bias concat
        if (tidx < 256) {
            bqkv[tidx]       = bq[tidx];
            bqkv[tidx + 256] = bk[tidx];
            bqkv[tidx + 512] = bv[tidx];
        }
    } else {                              // x fp32 -> bf16 (float4 granules)
        const int i = (bid - 769) * 256 + tidx;
        if (i < NN * DIM / 4) {
            float4 v = ((const float4*)x)[i];
            u16x4 b = { f2b(v.x), f2b(v.y), f2b(v.z), f2b(v.w) };
            ((u16x4*)xb)[i] = b;
        }
    }
}

extern "C" void kernel_launch(void* const* d_in, const int* in_sizes, int n_in,
                              void* d_out, int out_size, void* d_ws, size_t ws_size,
                              hipStream_t stream)
{
    const float* x    = (const float*)d_in[0];
    const int*   samp = (const int*)  d_in[1];
    const float* Wq = (const float*)d_in[2];  const float* bq = (const float*)d_in[3];
    const float* Wk = (const float*)d_in[4];  const float* bk = (const float*)d_in[5];
    const float* Wv = (const float*)d_in[6];  const float* bv = (const float*)d_in[7];
    const float* Wo = (const float*)d_in[8];  const float* bo = (const float*)d_in[9];
    const float* W1 = (const float*)d_in[10]; const float* b1 = (const float*)d_in[11];
    const float* W2 = (const float*)d_in[12]; const float* b2 = (const float*)d_in[13];
    const float* g1 = (const float*)d_in[14]; const float* be1 = (const float*)d_in[15];
    const float* g2 = (const float*)d_in[16]; const float* be2 = (const float*)d_in[17];
    float* out = (float*)d_out;

    char* w = (char*)d_ws;
    const size_t MB = 1u << 20;
    // weights (live whole launch): 0 .. 2 MB
    unsigned short* WqkvT = (unsigned short*)(w + 0);          // [768][256] bf16
    unsigned short* WoT   = (unsigned short*)(w + 393216);     // [256][256]
    unsigned short* W1T   = (unsigned short*)(w + 524288);     // [1024][256]
    unsigned short* W2T   = (unsigned short*)(w + 1048576);    // [256][1024]
    float*          bqkv  = (float*)(w + 1572864);             // [768]
    // activations — NON-OVERLAPPING liveness map:
    //   xb 2..12.24MB (live through LN1 as bf16 residual) | qb 13..23.24
    //   kvp 24..34.24 | ob 35..45.24 | x1b 46..56.24 | hmid 57..97.96
    unsigned short* xb    = (unsigned short*)(w + 2 * MB);     // [NN][256] bf16
    unsigned short* qb    = (unsigned short*)(w + 13 * MB);    // [NN][256] bf16
    unsigned char*  kvp   = (unsigned char*) (w + 24 * MB);    // [4][NN][128] fp8
    unsigned short* ob    = (unsigned short*)(w + 35 * MB);    // [NN][256] bf16
    unsigned short* x1b   = (unsigned short*)(w + 46 * MB);    // [NN][256] bf16; live to LN2
    unsigned short* hmid  = (unsigned short*)(w + 57 * MB);    // [NN][1024] bf16

    const dim3 blk(256);

    // ---- fused prep (one launch) ----
    prep_all<<<dim3(769 + NN * DIM / 4 / 256), blk, 0, stream>>>(
        Wq, Wk, Wv, Wo, W1, W2, bq, bk, bv, x,
        WqkvT, WoT, W1T, W2T, bqkv, xb);

    // ---- fused QKV projection: Q->bf16, K/V->fp8 head-pair layout (swizzled grid) ----
    gemm_mfma<128, 6, 0, 0, 0, 1><<<dim3(157 * 6), blk, 0, stream>>>(
        xb, WqkvT, bqkv, nullptr, qb, kvp, NN, QKVD, DIM);

    // ---- attention (head-pair per XCD, 2 nodes/wave) ----
    attn_f8<<<dim3(NN / 2), blk, 0, stream>>>(qb, kvp, samp, ob);

    // ---- out proj + residual(xb bf16) + LN1 fused -> x1b bf16 ----
    gemm_ln<0, 0><<<dim3(NN / 32), blk, 0, stream>>>(
        ob, WoT, bo, nullptr, xb, g1, be1, nullptr, x1b, NN, DIM);

    // ---- FFN1 (swizzled grid) ----
    gemm_mfma<128, 8, 1, 0, 1, 0><<<dim3(157 * 8), blk, 0, stream>>>(
        x1b, W1T, b1, nullptr, hmid, nullptr, NN, DFFN, DIM);

    // ---- FFN2 + residual(x1b bf16) + LN2 fused -> out f32 ----
    gemm_ln<0, 1><<<dim3(NN / 32), blk, 0, stream>>>(
        hmid, W2T, b2, nullptr, x1b, g2, be2, out, nullptr, NN, DFFN);
}

// Round 21
// 156.628 us; speedup vs baseline: 1.0172x; 1.0172x over previous
//
#include <hip/hip_runtime.h>

#define NN 20000
#define KNEI 32
#define DIM 256
#define NHEAD 8
#define HDIM 32
#define DFFN 1024
#define QKVD 768

typedef __attribute__((ext_vector_type(8))) __bf16 bf16x8;
typedef __attribute__((ext_vector_type(8))) unsigned short u16x8;
typedef __attribute__((ext_vector_type(4))) unsigned short u16x4;
typedef __attribute__((ext_vector_type(4))) float f32x4;
typedef __attribute__((ext_vector_type(2))) float f32x2;

static __device__ __forceinline__ float b2f(unsigned short u) {
    return __builtin_bit_cast(float, (unsigned)u << 16);
}
static __device__ __forceinline__ float blo(unsigned w) {
    return __builtin_bit_cast(float, w << 16);
}
static __device__ __forceinline__ float bhi(unsigned w) {
    return __builtin_bit_cast(float, w & 0xffff0000u);
}
static __device__ __forceinline__ unsigned short f2b(float f) {
    unsigned u = __builtin_bit_cast(unsigned, f);
    return (unsigned short)((u + 0x7fff + ((u >> 16) & 1)) >> 16);
}

// ---- fp8 e4m3fn encode/decode (HW builtins on device; bit-ops fallback for host pass) ----
static __device__ __forceinline__ unsigned char fp8enc(float v) {
#if defined(__HIP_DEVICE_COMPILE__) && __has_builtin(__builtin_amdgcn_cvt_pk_fp8_f32)
    return (unsigned char)(__builtin_amdgcn_cvt_pk_fp8_f32(v, v, 0u, false) & 0xffu);
#else
    unsigned u = __builtin_bit_cast(unsigned, v);
    unsigned s = u >> 31;
    unsigned a = u & 0x7fffffffu;
    if (a >= 0x43e00000u) return (unsigned char)((s << 7) | 0x7e);
    float af = __builtin_bit_cast(float, a);
    if (af < 0.015625f) {
        unsigned r = (unsigned)(af * 512.0f + 0.5f);
        if (r >= 8u) return (unsigned char)((s << 7) | 0x08);
        return (unsigned char)((s << 7) | r);
    }
    unsigned lsb = (a >> 20) & 1u;
    a += 0x7ffffu + lsb;
    unsigned e = (a >> 23) - 120u;
    unsigned m = (a >> 20) & 7u;
    unsigned code = (e << 3) | m;
    if (code > 0x7eu) code = 0x7eu;
    return (unsigned char)((s << 7) | code);
#endif
}

template<int SEL>
static __device__ __forceinline__ float fp8dec(unsigned word) {
#if defined(__HIP_DEVICE_COMPILE__) && __has_builtin(__builtin_amdgcn_cvt_f32_fp8)
    return __builtin_amdgcn_cvt_f32_fp8(word, SEL);
#else
    unsigned b = (word >> (SEL * 8)) & 0xffu;
    unsigned s = (b >> 7) & 1u;
    unsigned e = (b >> 3) & 0xfu;
    unsigned m = b & 7u;
    float v;
    if (e == 0) v = (float)m * 0.001953125f;
    else        v = __builtin_bit_cast(float, ((e + 120u) << 23) | (m << 20));
    return s ? -v : v;
#endif
}

template<bool HI>
static __device__ __forceinline__ f32x2 fp8pk(unsigned word) {
#if defined(__HIP_DEVICE_COMPILE__) && __has_builtin(__builtin_amdgcn_cvt_pk_f32_fp8)
    return __builtin_amdgcn_cvt_pk_f32_fp8((int)word, HI);
#else
    f32x2 r;
    r.x = fp8dec<HI ? 2 : 0>(word);
    r.y = fp8dec<HI ? 3 : 1>(word);
    return r;
#endif
}

#define GLD16(src, dst)                                                          \
    __builtin_amdgcn_global_load_lds(                                            \
        (const __attribute__((address_space(1))) void*)(const void*)(src),       \
        (__attribute__((address_space(3))) void*)(void*)(dst), 16, 0, 0)

// ---------------- bf16 MFMA GEMM (r12 structure) + XCD-aware block swizzle ----------------
template<int BM, int NT, int RELU, int WF32, int WBF16, int SPLIT>
__global__ __launch_bounds__(256) void gemm_mfma(const unsigned short* __restrict__ A,
                                                 const unsigned short* __restrict__ Bt,
                                                 const float* __restrict__ bias,
                                                 float* __restrict__ Cf,
                                                 unsigned short* __restrict__ Cb,
                                                 unsigned char* __restrict__ kvp,
                                                 int M, int N, int K)
{
    constexpr int BN = 128, BK = 32;
    constexpr int MI = BM / 32;
    constexpr int NI = BN / 32;

    __shared__ unsigned short As[BM * BK];
    __shared__ unsigned short Bs[BN * BK];

    const int tid  = threadIdx.x;
    const int wid  = tid >> 6;
    const int lane = tid & 63;

    // ---- bijective XCD swizzle; N-fastest within each XCD chunk ----
    const int nwg  = gridDim.x;
    const int orig = blockIdx.x;
    const int xcd  = orig & 7;
    const int pos  = orig >> 3;
    const int qc   = nwg >> 3, rc = nwg & 7;
    const int wgid = (xcd < rc ? xcd * (qc + 1) : rc * (qc + 1) + (xcd - rc) * qc) + pos;
    const int bm = (wgid / NT) * BM;
    const int bn = (wgid % NT) * BN;

    const int wr = (wid >> 1) * (BM / 2);
    const int wc = (wid & 1) * (BN / 2);
    const int r0   = lane & 15;
    const int kblk = (lane >> 4) * 8;

    f32x4 acc[MI][NI];
    #pragma unroll
    for (int i = 0; i < MI; ++i)
        #pragma unroll
        for (int j = 0; j < NI; ++j)
            acc[i][j] = (f32x4){0.f, 0.f, 0.f, 0.f};

    for (int k0 = 0; k0 < K; k0 += BK) {
        #pragma unroll
        for (int t = 0; t < (BM * 4) / 256; ++t) {
            int c = t * 256 + tid;
            int row = bm + (c >> 2);
            if (row >= M) row = M - 1;
            GLD16(A + (size_t)row * K + k0 + (c & 3) * 8,
                  &As[(t * 256 + wid * 64) * 8]);
        }
        #pragma unroll
        for (int t = 0; t < (BN * 4) / 256; ++t) {
            int c = t * 256 + tid;
            GLD16(Bt + (size_t)(bn + (c >> 2)) * K + k0 + (c & 3) * 8,
                  &Bs[(t * 256 + wid * 64) * 8]);
        }
        __syncthreads();

        bf16x8 af[MI], bfr[NI];
        #pragma unroll
        for (int mi = 0; mi < MI; ++mi)
            af[mi] = __builtin_bit_cast(bf16x8,
                     *(const u16x8*)&As[(wr + mi * 16 + r0) * BK + kblk]);
        #pragma unroll
        for (int ni = 0; ni < NI; ++ni)
            bfr[ni] = __builtin_bit_cast(bf16x8,
                     *(const u16x8*)&Bs[(wc + ni * 16 + r0) * BK + kblk]);
        #pragma unroll
        for (int mi = 0; mi < MI; ++mi)
            #pragma unroll
            for (int ni = 0; ni < NI; ++ni)
                acc[mi][ni] = __builtin_amdgcn_mfma_f32_16x16x32_bf16(
                    af[mi], bfr[ni], acc[mi][ni], 0, 0, 0);
        __syncthreads();
    }

    const int r4 = (lane >> 4) * 4;
    #pragma unroll
    for (int mi = 0; mi < MI; ++mi)
        #pragma unroll
        for (int ni = 0; ni < NI; ++ni) {
            const int col = bn + wc + ni * 16 + r0;
            const float bb = bias[col];
            #pragma unroll
            for (int r = 0; r < 4; ++r) {
                const int row = bm + wr + mi * 16 + r4 + r;
                if (row < M) {
                    float v = acc[mi][ni][r] + bb;
                    if (RELU) v = fmaxf(v, 0.f);
                    if (SPLIT) {
                        if (col < 256) {
                            Cb[(size_t)row * DIM + col] = f2b(v);
                        } else {
                            const int cc  = col - 256;          // 0..511
                            const int isV = cc >> 8;            // 0=K, 1=V
                            const int hh  = (cc & 255) >> 5;    // head 0..7
                            const int dd  = cc & 31;
                            kvp[((size_t)(hh >> 1) * NN + row) * 128
                                + isV * 64 + (hh & 1) * 32 + dd] = fp8enc(v);
                        }
                    } else {
                        if (WF32)  Cf[(size_t)row * N + col] = v;
                        if (WBF16) Cb[(size_t)row * N + col] = f2b(v);
                    }
                }
            }
        }
}

// ---------------- fused GEMM (N=256) + residual + LayerNorm epilogue (BM=32) ----------
template<int RESF32, int WFOUT>
__global__ __launch_bounds__(256) void gemm_ln(const unsigned short* __restrict__ A,
                                               const unsigned short* __restrict__ Bt,
                                               const float* __restrict__ bias,
                                               const float* __restrict__ resf,
                                               const unsigned short* __restrict__ resb,
                                               const float* __restrict__ gamma,
                                               const float* __restrict__ beta,
                                               float* __restrict__ outf,
                                               unsigned short* __restrict__ outb,
                                               int M, int K)
{
    constexpr int BM = 32, BN = 256, BK = 32;
    constexpr int NI = BN / 32;   // 8

    __shared__ unsigned short As[BM * BK];
    __shared__ unsigned short Bs[BN * BK];
    __shared__ float rs[2][BM][2];   // [col-half][local row][sum, sumsq]

    const int tid  = threadIdx.x;
    const int wid  = tid >> 6;
    const int lane = tid & 63;
    const int bm = blockIdx.x * BM;
    const int wr = (wid >> 1) * 16;          // 16-row half
    const int wc = (wid & 1) * 128;          // 128-col half
    const int r0   = lane & 15;
    const int kblk = (lane >> 4) * 8;

    f32x4 acc[NI];
    #pragma unroll
    for (int j = 0; j < NI; ++j) acc[j] = (f32x4){0.f, 0.f, 0.f, 0.f};

    for (int k0 = 0; k0 < K; k0 += BK) {
        if (wid < 2) {
            int c = tid;  // 0..127
            GLD16(A + (size_t)(bm + (c >> 2)) * K + k0 + (c & 3) * 8,
                  &As[(wid * 64) * 8]);
        }
        #pragma unroll
        for (int t = 0; t < 4; ++t) {
            int c = t * 256 + tid;
            GLD16(Bt + (size_t)(c >> 2) * K + k0 + (c & 3) * 8,
                  &Bs[(t * 256 + wid * 64) * 8]);
        }
        __syncthreads();

        bf16x8 af = __builtin_bit_cast(bf16x8,
                    *(const u16x8*)&As[(wr + r0) * BK + kblk]);
        bf16x8 bfr[NI];
        #pragma unroll
        for (int ni = 0; ni < NI; ++ni)
            bfr[ni] = __builtin_bit_cast(bf16x8,
                      *(const u16x8*)&Bs[(wc + ni * 16 + r0) * BK + kblk]);
        #pragma unroll
        for (int ni = 0; ni < NI; ++ni)
            acc[ni] = __builtin_amdgcn_mfma_f32_16x16x32_bf16(af, bfr[ni], acc[ni], 0, 0, 0);
        __syncthreads();
    }

    // ---- epilogue: v = acc + bias + residual; per-row LN over 256 cols ----
    const int r4 = (lane >> 4) * 4;
    float v[NI][4];
    float rsum[4] = {0.f, 0.f, 0.f, 0.f};
    float rsq[4]  = {0.f, 0.f, 0.f, 0.f};
    #pragma unroll
    for (int ni = 0; ni < NI; ++ni) {
        const int col = wc + ni * 16 + r0;
        const float bb = bias[col];
        #pragma unroll
        for (int r = 0; r < 4; ++r) {
            const size_t idx = (size_t)(bm + wr + r4 + r) * DIM + col;
            const float res = RESF32 ? resf[idx] : b2f(resb[idx]);
            const float val = acc[ni][r] + bb + res;
            v[ni][r] = val;
            rsum[r] += val;
            rsq[r]  += val * val;
        }
    }
    #pragma unroll
    for (int sh = 1; sh <= 8; sh <<= 1) {
        #pragma unroll
        for (int r = 0; r < 4; ++r) {
            rsum[r] += __shfl_xor(rsum[r], sh);
            rsq[r]  += __shfl_xor(rsq[r], sh);
        }
    }
    if (r0 == 0) {
        #pragma unroll
        for (int r = 0; r < 4; ++r) {
            rs[wid & 1][wr + r4 + r][0] = rsum[r];
            rs[wid & 1][wr + r4 + r][1] = rsq[r];
        }
    }
    __syncthreads();
    float mean_r[4], rstd_r[4];
    #pragma unroll
    for (int r = 0; r < 4; ++r) {
        const int lrow = wr + r4 + r;
        const float sum = rs[0][lrow][0] + rs[1][lrow][0];
        const float sq  = rs[0][lrow][1] + rs[1][lrow][1];
        const float mean = sum * (1.f / 256.f);
        mean_r[r] = mean;
        rstd_r[r] = rsqrtf(sq * (1.f / 256.f) - mean * mean + 1e-5f);
    }
    #pragma unroll
    for (int ni = 0; ni < NI; ++ni) {
        const int col = wc + ni * 16 + r0;
        const float g = gamma[col], be = beta[col];
        #pragma unroll
        for (int r = 0; r < 4; ++r) {
            const size_t idx = (size_t)(bm + wr + r4 + r) * DIM + col;
            const float ov = (v[ni][r] - mean_r[r]) * rstd_r[r] * g + be;
            if (WFOUT) outf[idx] = ov;
            else       outb[idx] = f2b(ov);
        }
    }
}

// ---------------- attention (r12 variant — best measured: 46.0 µs, 71% occ) ----------------
// kvp[hp][node][128]: K(2hp) K(2hp+1) V(2hp) V(2hp+1), 32 B each.
__global__ __launch_bounds__(256) void attn_f8(const unsigned short* __restrict__ q,
                                               const unsigned char* __restrict__ kvp,
                                               const int* __restrict__ samp,
                                               unsigned short* __restrict__ o)
{
    __shared__ int pkbuf[4][128];   // per wave: [hs][j] interleaved (p, koff) pairs

    const int bid = blockIdx.x;
    const int hp  = bid & 3;
    const int tid = threadIdx.x;
    const int wid = tid >> 6;
    const int n   = (bid >> 2) * 4 + wid;
    const int lane = tid & 63;
    const int j = lane & 31;
    const int hs = lane >> 5;
    const int h = hp * 2 + hs;

    const int kidx = samp[n * KNEI + j];

    const uint4* qp = (const uint4*)(q + (size_t)n * DIM + h * HDIM);
    const uint4 qa = qp[0], qb = qp[1], qc = qp[2], qd = qp[3];
    const unsigned qw[16] = {qa.x, qa.y, qa.z, qa.w, qb.x, qb.y, qb.z, qb.w,
                             qc.x, qc.y, qc.z, qc.w, qd.x, qd.y, qd.z, qd.w};

    const unsigned char* krow = kvp + ((size_t)hp * NN + kidx) * 128 + hs * 32;
    const uint4 k0 = *(const uint4*)krow;
    const uint4 k1 = *(const uint4*)(krow + 16);
    const unsigned kw[8] = {k0.x, k0.y, k0.z, k0.w, k1.x, k1.y, k1.z, k1.w};

    float s = 0.f;
    #pragma unroll
    for (int i = 0; i < 8; ++i) {
        f32x2 ka = fp8pk<false>(kw[i]);
        f32x2 kb = fp8pk<true>(kw[i]);
        unsigned q0 = qw[2 * i], q1 = qw[2 * i + 1];
        s = fmaf(blo(q0), ka.x, s);
        s = fmaf(bhi(q0), ka.y, s);
        s = fmaf(blo(q1), kb.x, s);
        s = fmaf(bhi(q1), kb.y, s);
    }
    s *= 0.17677669529663687f;              // 1/sqrt(32)

    float m = s;
    #pragma unroll
    for (int sh = 16; sh; sh >>= 1) m = fmaxf(m, __shfl_xor(m, sh));
    float e = __expf(s - m);
    float sum = e;
    #pragma unroll
    for (int sh = 16; sh; sh >>= 1) sum += __shfl_xor(sum, sh);
    const float p = __fdividef(e, sum);

    pkbuf[wid][hs * 64 + j * 2]     = __builtin_bit_cast(int, p);
    pkbuf[wid][hs * 64 + j * 2 + 1] = kidx << 7;

    const int jg = j >> 3, d8 = j & 7;
    const unsigned vconst = (unsigned)((size_t)hp * NN) * 128u + 64u + hs * 32 + d8 * 4;
    float a0 = 0.f, a1 = 0.f, a2 = 0.f, a3 = 0.f;
    #pragma unroll
    for (int jj = 0; jj < 8; ++jj) {
        const int jn = jg * 8 + jj;
        const int2 pk = *(const int2*)&pkbuf[wid][hs * 64 + jn * 2];  // ds_read_b64
        const float pj = __builtin_bit_cast(float, pk.x);
        const unsigned vw = *(const unsigned*)(kvp + vconst + (unsigned)pk.y);
        f32x2 vlo = fp8pk<false>(vw);
        f32x2 vhi = fp8pk<true>(vw);
        a0 = fmaf(pj, vlo.x, a0);
        a1 = fmaf(pj, vlo.y, a1);
        a2 = fmaf(pj, vhi.x, a2);
        a3 = fmaf(pj, vhi.y, a3);
    }
    a0 += __shfl_xor(a0, 8);  a1 += __shfl_xor(a1, 8);
    a2 += __shfl_xor(a2, 8);  a3 += __shfl_xor(a3, 8);
    a0 += __shfl_xor(a0, 16); a1 += __shfl_xor(a1, 16);
    a2 += __shfl_xor(a2, 16); a3 += __shfl_xor(a3, 16);
    if (jg == 0) {
        u16x4 ov = { f2b(a0), f2b(a1), f2b(a2), f2b(a3) };
        *(u16x4*)(o + (size_t)n * DIM + h * HDIM + d8 * 4) = ov;
    }
}

// ---------------- fused prep: all weight transposes + bias concat + x->bf16 ----------------
static __device__ __forceinline__ void trans_tile(const float* __restrict__ W,
                                                  unsigned short* __restrict__ T,
                                                  float (*sh)[33],
                                                  int n0, int k0, int N, int K, int tidx)
{
    const int tx = tidx & 31, ty = tidx >> 5;
    #pragma unroll
    for (int i = 0; i < 32; i += 8)
        sh[ty + i][tx] = W[(size_t)(k0 + ty + i) * N + n0 + tx];
    __syncthreads();
    #pragma unroll
    for (int i = 0; i < 32; i += 8)
        T[(size_t)(n0 + ty + i) * K + k0 + tx] = f2b(sh[tx][ty + i]);
}

__global__ __launch_bounds__(256) void prep_all(const float* __restrict__ Wq,
                                                const float* __restrict__ Wk,
                                                const float* __restrict__ Wv,
                                                const float* __restrict__ Wo,
                                                const float* __restrict__ W1,
                                                const float* __restrict__ W2,
                                                const float* __restrict__ bq,
                                                const float* __restrict__ bk,
                                                const float* __restrict__ bv,
                                                const float* __restrict__ x,
                                                unsigned short* __restrict__ WqkvT,
                                                unsigned short* __restrict__ WoT,
                                                unsigned short* __restrict__ W1T,
                                                unsigned short* __restrict__ W2T,
                                                float* __restrict__ bqkv,
                                                unsigned short* __restrict__ xb)
{
    __shared__ float sh[32][33];
    const int bid = blockIdx.x;
    const int tidx = threadIdx.x;

    if (bid < 256) {                      // 4 x [256][256] -> [256][256]^T
        const float* W; unsigned short* T;
        switch (bid >> 6) {
            case 0:  W = Wq; T = WqkvT;           break;
            case 1:  W = Wk; T = WqkvT + 65536;   break;
            case 2:  W = Wv; T = WqkvT + 131072;  break;
            default: W = Wo; T = WoT;             break;
        }
        const int t = bid & 63;
        trans_tile(W, T, sh, (t & 7) * 32, (t >> 3) * 32, DIM, DIM, tidx);
    } else if (bid < 512) {               // W1 [256][1024] -> [1024][256]
        const int t = bid - 256;
        trans_tile(W1, W1T, sh, (t & 31) * 32, (t >> 5) * 32, DFFN, DIM, tidx);
    } else if (bid < 768) {               // W2 [1024][256] -> [256][1024]
        const int t = bid - 512;
        trans_tile(W2, W2T, sh, (t & 7) * 32, (t >> 3) * 32, DIM, DFFN, tidx);
    } else if (bid == 768) {              // bias concat
        if (tidx < 256) {
            bqkv[tidx]       = bq[tidx];
            bqkv[tidx + 256] = bk[tidx];
            bqkv[tidx + 512] = bv[tidx];
        }
    } else {                              // x fp32 -> bf16 (float4 granules)
        const int i = (bid - 769) * 256 + tidx;
        if (i < NN * DIM / 4) {
            float4 v = ((const float4*)x)[i];
            u16x4 b = { f2b(v.x), f2b(v.y), f2b(v.z), f2b(v.w) };
            ((u16x4*)xb)[i] = b;
        }
    }
}

extern "C" void kernel_launch(void* const* d_in, const int* in_sizes, int n_in,
                              void* d_out, int out_size, void* d_ws, size_t ws_size,
                              hipStream_t stream)
{
    const float* x    = (const float*)d_in[0];
    const int*   samp = (const int*)  d_in[1];
    const float* Wq = (const float*)d_in[2];  const float* bq = (const float*)d_in[3];
    const float* Wk = (const float*)d_in[4];  const float* bk = (const float*)d_in[5];
    const float* Wv = (const float*)d_in[6];  const float* bv = (const float*)d_in[7];
    const float* Wo = (const float*)d_in[8];  const float* bo = (const float*)d_in[9];
    const float* W1 = (const float*)d_in[10]; const float* b1 = (const float*)d_in[11];
    const float* W2 = (const float*)d_in[12]; const float* b2 = (const float*)d_in[13];
    const float* g1 = (const float*)d_in[14]; const float* be1 = (const float*)d_in[15];
    const float* g2 = (const float*)d_in[16]; const float* be2 = (const float*)d_in[17];
    float* out = (float*)d_out;

    char* w = (char*)d_ws;
    const size_t MB = 1u << 20;
    // weights (live whole launch): 0 .. 2 MB
    unsigned short* WqkvT = (unsigned short*)(w + 0);          // [768][256] bf16
    unsigned short* WoT   = (unsigned short*)(w + 393216);     // [256][256]
    unsigned short* W1T   = (unsigned short*)(w + 524288);     // [1024][256]
    unsigned short* W2T   = (unsigned short*)(w + 1048576);    // [256][1024]
    float*          bqkv  = (float*)(w + 1572864);             // [768]
    // activations — NON-OVERLAPPING liveness map:
    //   xb 2..12.24MB (live through LN1 as bf16 residual) | qb 13..23.24
    //   kvp 24..34.24 | ob 35..45.24 | x1b 46..56.24 | hmid 57..97.96
    unsigned short* xb    = (unsigned short*)(w + 2 * MB);     // [NN][256] bf16
    unsigned short* qb    = (unsigned short*)(w + 13 * MB);    // [NN][256] bf16
    unsigned char*  kvp   = (unsigned char*) (w + 24 * MB);    // [4][NN][128] fp8
    unsigned short* ob    = (unsigned short*)(w + 35 * MB);    // [NN][256] bf16
    unsigned short* x1b   = (unsigned short*)(w + 46 * MB);    // [NN][256] bf16; live to LN2
    unsigned short* hmid  = (unsigned short*)(w + 57 * MB);    // [NN][1024] bf16

    const dim3 blk(256);

    // ---- fused prep (one launch) ----
    prep_all<<<dim3(769 + NN * DIM / 4 / 256), blk, 0, stream>>>(
        Wq, Wk, Wv, Wo, W1, W2, bq, bk, bv, x,
        WqkvT, WoT, W1T, W2T, bqkv, xb);

    // ---- fused QKV projection: Q->bf16, K/V->fp8 head-pair layout (swizzled grid) ----
    gemm_mfma<128, 6, 0, 0, 0, 1><<<dim3(157 * 6), blk, 0, stream>>>(
        xb, WqkvT, bqkv, nullptr, qb, kvp, NN, QKVD, DIM);

    // ---- attention (head-pair per XCD, jgroup PV) ----
    attn_f8<<<dim3(NN), blk, 0, stream>>>(qb, kvp, samp, ob);

    // ---- out proj + residual(xb bf16) + LN1 fused -> x1b bf16 ----
    gemm_ln<0, 0><<<dim3(NN / 32), blk, 0, stream>>>(
        ob, WoT, bo, nullptr, xb, g1, be1, nullptr, x1b, NN, DIM);

    // ---- FFN1 (swizzled grid) ----
    gemm_mfma<128, 8, 1, 0, 1, 0><<<dim3(157 * 8), blk, 0, stream>>>(
        x1b, W1T, b1, nullptr, hmid, nullptr, NN, DFFN, DIM);

    // ---- FFN2 + residual(x1b bf16) + LN2 fused -> out f32 ----
    gemm_ln<0, 1><<<dim3(NN / 32), blk, 0, stream>>>(
        hmid, W2T, b2, nullptr, x1b, g2, be2, out, nullptr, NN, DFFN);
}